// Round 6
// baseline (661.686 us; speedup 1.0000x reference)
//
#include <hip/hip_runtime.h>
#include <hip/hip_bf16.h>
#include <math.h>

#define NNODES 10000
#define NEDGES 160000
#define ETOT (NEDGES + NNODES)  // edges + self-loops
#define HEADS 7
#define CH 64
#define HC 448    // HEADS*CH
#define HCP 1024  // padded fused width: [xl 512 | xr 512], slot = half*512+c*8+h

typedef __attribute__((ext_vector_type(8))) short short8;
typedef __attribute__((ext_vector_type(4))) float floatx4;

__device__ __forceinline__ float bf_lo(unsigned u) {
  return __uint_as_float(u << 16);
}
__device__ __forceinline__ float bf_hi(unsigned u) {
  return __uint_as_float(u & 0xffff0000u);
}

// ---------------------------------------------------------------------------
// Conversion / packing kernels
// ---------------------------------------------------------------------------
__global__ __launch_bounds__(256) void convert_f32_bf16(
    const float* __restrict__ in, short* __restrict__ out, int n4) {
  int i = blockIdx.x * 256 + threadIdx.x;
  if (i < n4) {
    float4 v = *(const float4*)&in[(size_t)i * 4];
    short4 o;
    o.x = __bfloat16_as_short(__float2bfloat16(v.x));
    o.y = __bfloat16_as_short(__float2bfloat16(v.y));
    o.z = __bfloat16_as_short(__float2bfloat16(v.z));
    o.w = __bfloat16_as_short(__float2bfloat16(v.w));
    *(short4*)&out[(size_t)i * 4] = o;
  }
}

__global__ __launch_bounds__(256) void transpose_bf16(
    const float* __restrict__ in, short* __restrict__ out, int K, int N) {
  int idx = blockIdx.x * 256 + threadIdx.x;
  if (idx < K * N) {
    int n = idx / K, k = idx % K;
    out[idx] = __bfloat16_as_short(__float2bfloat16(in[(size_t)k * N + n]));
  }
}

// Wgt[l][col'][k], col' = half*512 + c*8 + h (h==7 -> zero pad). bg likewise.
__global__ __launch_bounds__(256) void pack_gat(
    const float* __restrict__ Wl, const float* __restrict__ Wr,
    const float* __restrict__ bl, short* __restrict__ Wgt,
    float* __restrict__ bg) {
  int idx = blockIdx.x * 256 + threadIdx.x;
  if (idx < 5 * HCP * 64) {
    int l = idx / (HCP * 64);
    int rem = idx % (HCP * 64);
    int col = rem / 64, k = rem % 64;
    int half = col >> 9;
    int within = col & 511;
    int c = within >> 3, h = within & 7;
    float v = 0.f;
    if (h < 7) {
      const float* W = half ? Wr : Wl;
      v = W[((size_t)l * 64 + k) * HC + h * 64 + c];
    }
    Wgt[idx] = __bfloat16_as_short(__float2bfloat16(v));
  }
  if (idx < 5 * HCP) {
    int l = idx >> 10, col = idx & 1023;
    int half = col >> 9, within = col & 511;
    int c = within >> 3, h = within & 7;
    bg[idx] = (!half && h < 7) ? bl[(size_t)l * HC + h * 64 + c] : 0.f;
  }
}

// ---------------------------------------------------------------------------
// MFMA bf16 GEMM: C = act(A @ Bt^T + bias), bf16 row-major out.
// ---------------------------------------------------------------------------
template <int BM, int BN, int RELU>
__global__ __launch_bounds__(256) void mfma_gemm(
    const short* __restrict__ A, const short* __restrict__ Bt,
    const float* __restrict__ bias, short* __restrict__ C,
    int M, int K, int Nc) {
  __shared__ short As[BM * 64];
  __shared__ short Bs[BN * 64];
  constexpr int MI = BM / 32;
  constexpr int NJ = BN / 32;
  int tid = threadIdx.x;
  int lane = tid & 63, wave = tid >> 6;
  int wm = wave >> 1, wn = wave & 1;
  int row0 = blockIdx.x * BM, col0 = blockIdx.y * BN;
  floatx4 acc[MI][NJ] = {};

  for (int k0 = 0; k0 < K; k0 += 64) {
    #pragma unroll
    for (int i = 0; i < BM / 32; ++i) {
      int c = i * 4 + wave;
      int r = c * 8 + (lane >> 3);
      int k = (lane & 7) * 8;
      int grow = row0 + r;
      if (grow >= M) grow = M - 1;
      __builtin_amdgcn_global_load_lds(
          (const __attribute__((address_space(1))) void*)(A + (size_t)grow * K + k0 + k),
          (__attribute__((address_space(3))) void*)(As + c * 512), 16, 0, 0);
    }
    #pragma unroll
    for (int i = 0; i < BN / 32; ++i) {
      int c = i * 4 + wave;
      int r = c * 8 + (lane >> 3);
      int k = (lane & 7) * 8;
      int gcol = col0 + r;
      if (gcol >= Nc) gcol = Nc - 1;
      __builtin_amdgcn_global_load_lds(
          (const __attribute__((address_space(1))) void*)(Bt + (size_t)gcol * K + k0 + k),
          (__attribute__((address_space(3))) void*)(Bs + c * 512), 16, 0, 0);
    }
    __syncthreads();
    int lr = lane & 15, lq = lane >> 4;
    #pragma unroll
    for (int kk = 0; kk < 64; kk += 32) {
      short8 af[MI], bf[NJ];
      #pragma unroll
      for (int i = 0; i < MI; ++i)
        af[i] = *(const short8*)&As[(wm * (BM / 2) + i * 16 + lr) * 64 + kk + lq * 8];
      #pragma unroll
      for (int j = 0; j < NJ; ++j)
        bf[j] = *(const short8*)&Bs[(wn * (BN / 2) + j * 16 + lr) * 64 + kk + lq * 8];
      #pragma unroll
      for (int i = 0; i < MI; ++i)
        #pragma unroll
        for (int j = 0; j < NJ; ++j)
          acc[i][j] = __builtin_amdgcn_mfma_f32_16x16x32_bf16(
              af[i], bf[j], acc[i][j], 0, 0, 0);
    }
    __syncthreads();
  }

  int lr = lane & 15, lq = lane >> 4;
  #pragma unroll
  for (int j = 0; j < NJ; ++j) {
    int col = col0 + wn * (BN / 2) + j * 16 + lr;
    float bj = bias ? bias[col] : 0.f;
    #pragma unroll
    for (int i = 0; i < MI; ++i) {
      int rbase = row0 + wm * (BM / 2) + i * 16 + lq * 4;
      #pragma unroll
      for (int r = 0; r < 4; ++r) {
        int row = rbase + r;
        if (row < M) {
          float v = acc[i][j][r] + bj;
          if (RELU) v = fmaxf(v, 0.f);
          C[(size_t)row * Nc + col] = __bfloat16_as_short(__float2bfloat16(v));
        }
      }
    }
  }
}

// ---------------------------------------------------------------------------
// CSR build (dst-grouped, self-loops included).
// ---------------------------------------------------------------------------
__global__ void init_cnt(int* __restrict__ cnt) {
  int i = blockIdx.x * 256 + threadIdx.x;
  if (i < NNODES) cnt[i] = 1;  // self-loop
}

__global__ void hist_kernel(const int* __restrict__ ei, int* __restrict__ cnt) {
  int e = blockIdx.x * 256 + threadIdx.x;
  if (e < NEDGES) atomicAdd(&cnt[ei[NEDGES + e]], 1);
}

// single-block shuffle-based scan
__global__ __launch_bounds__(1024) void scan_kernel(
    const int* __restrict__ cnt, int* __restrict__ row_start,
    int* __restrict__ cursor) {
  __shared__ int wsum[16];
  int t = threadIdx.x;
  int lane = t & 63, w = t >> 6;
  int base = t * 10;
  int v[10], s = 0;
  #pragma unroll
  for (int i = 0; i < 10; ++i) {
    v[i] = (base + i < NNODES) ? cnt[base + i] : 0;
    s += v[i];
  }
  int incl = s;
  #pragma unroll
  for (int off = 1; off < 64; off <<= 1) {
    int o = __shfl_up(incl, off, 64);
    if (lane >= off) incl += o;
  }
  if (lane == 63) wsum[w] = incl;
  __syncthreads();
  if (w == 0) {
    int wv = (lane < 16) ? wsum[lane] : 0;
    #pragma unroll
    for (int off = 1; off < 16; off <<= 1) {
      int o = __shfl_up(wv, off, 64);
      if (lane >= off) wv += o;
    }
    if (lane < 16) wsum[lane] = wv;
  }
  __syncthreads();
  int woff = (w > 0) ? wsum[w - 1] : 0;
  int excl = woff + incl - s;
  #pragma unroll
  for (int i = 0; i < 10; ++i) {
    if (base + i < NNODES) {
      row_start[base + i] = excl;
      cursor[base + i] = excl;
    }
    excl += v[i];
  }
  if (t == 1023) row_start[NNODES] = wsum[15];
}

__global__ void scatter_self(int* __restrict__ cursor,
                             int* __restrict__ csr_src) {
  int n = blockIdx.x * 256 + threadIdx.x;
  if (n < NNODES) {
    int pos = atomicAdd(&cursor[n], 1);
    csr_src[pos] = n;
  }
}

__global__ void scatter_kernel(const int* __restrict__ ei,
                               int* __restrict__ cursor,
                               int* __restrict__ csr_src) {
  int e = blockIdx.x * 256 + threadIdx.x;
  if (e < NEDGES) {
    int d = ei[NEDGES + e];
    int pos = atomicAdd(&cursor[d], 1);
    csr_src[pos] = ei[e];
  }
}

// ---------------------------------------------------------------------------
// Fused GATv2 layer: logits + online softmax + aggregation. Wave per dst.
// Chunk of 8 edges: phase A computes logits (8 lanes/edge, xr in regs),
// online max/rescale; phase B re-reads xl rows (L1-hot) lane=channel.
// ---------------------------------------------------------------------------
__global__ __launch_bounds__(256) void gat_fused_kernel(
    const short* __restrict__ xlt, const float* __restrict__ att,
    const float* __restrict__ cbias, const int* __restrict__ row_start,
    const int* __restrict__ csr_src, short* __restrict__ hout) {
  __shared__ float att_s[512];  // att_t[c][h]
  __shared__ float alpha_s[4][64];
  for (int i = threadIdx.x; i < 512; i += 256) {
    int c = i >> 3, h = i & 7;
    att_s[i] = (h < 7) ? att[h * 64 + c] : 0.f;
  }
  __syncthreads();
  int lane = threadIdx.x & 63;
  int wid = threadIdx.x >> 6;
  int n = blockIdx.x * 4 + wid;
  if (n >= NNODES) return;
  int beg = row_start[n], end = row_start[n + 1];
  int eo = lane >> 3, cl = lane & 7;

  // preload this node's xr row: channel c = q*8+cl for q=0..7 (32 VGPRs)
  uint4 xr[8];
  #pragma unroll
  for (int q = 0; q < 8; ++q)
    xr[q] = *(const uint4*)(xlt + (size_t)n * HCP + 512 + (size_t)(q * 8 + cl) * 8);

  float M = -1e30f;   // running max for head (hm = cl), wave-uniform over eo
  float ssum = 0.f;   // this lane's eo-strided partial sum-exp for head cl
  float o0 = 0.f, o1 = 0.f, o2 = 0.f, o3 = 0.f, o4 = 0.f, o5 = 0.f, o6 = 0.f;

  for (int g = beg; g < end; g += 8) {
    int lim = end - g;
    if (lim > 8) lim = 8;
    int e = g + eo;
    int src = csr_src[(e < end) ? e : (end - 1)];

    // ---- phase A: logits for up to 8 edges
    float a0 = 0.f, a1 = 0.f, a2 = 0.f, a3 = 0.f, a4 = 0.f, a5 = 0.f, a6 = 0.f;
    const short* xlp = xlt + (size_t)src * HCP;
    #pragma unroll
    for (int q = 0; q < 8; ++q) {
      int c = q * 8 + cl;
      uint4 a = *(const uint4*)(xlp + (size_t)c * 8);
      uint4 b = xr[q];
      float4 t0 = *(const float4*)&att_s[c * 8];
      float4 t1 = *(const float4*)&att_s[c * 8 + 4];
      float e0 = bf_lo(a.x) + bf_lo(b.x);
      float e1 = bf_hi(a.x) + bf_hi(b.x);
      float e2 = bf_lo(a.y) + bf_lo(b.y);
      float e3 = bf_hi(a.y) + bf_hi(b.y);
      float e4 = bf_lo(a.z) + bf_lo(b.z);
      float e5 = bf_hi(a.z) + bf_hi(b.z);
      float e6 = bf_lo(a.w) + bf_lo(b.w);
      e0 = fmaxf(e0, 0.2f * e0); e1 = fmaxf(e1, 0.2f * e1);
      e2 = fmaxf(e2, 0.2f * e2); e3 = fmaxf(e3, 0.2f * e3);
      e4 = fmaxf(e4, 0.2f * e4); e5 = fmaxf(e5, 0.2f * e5);
      e6 = fmaxf(e6, 0.2f * e6);
      a0 += t0.x * e0; a1 += t0.y * e1;
      a2 += t0.z * e2; a3 += t0.w * e3;
      a4 += t1.x * e4; a5 += t1.y * e5;
      a6 += t1.z * e6;
    }
    // reduce over the 8-lane channel group (xor 1,2,4)
    #pragma unroll
    for (int st = 1; st <= 4; st <<= 1) {
      a0 += __shfl_xor(a0, st, 64); a1 += __shfl_xor(a1, st, 64);
      a2 += __shfl_xor(a2, st, 64); a3 += __shfl_xor(a3, st, 64);
      a4 += __shfl_xor(a4, st, 64); a5 += __shfl_xor(a5, st, 64);
      a6 += __shfl_xor(a6, st, 64);
    }
    float lg = -1e30f;
    lg = (cl == 0) ? a0 : lg; lg = (cl == 1) ? a1 : lg;
    lg = (cl == 2) ? a2 : lg; lg = (cl == 3) ? a3 : lg;
    lg = (cl == 4) ? a4 : lg; lg = (cl == 5) ? a5 : lg;
    lg = (cl == 6) ? a6 : lg;
    if (eo >= lim) lg = -1e30f;

    // ---- online softmax update (per-head, uniform over eo)
    float cm = lg;
    cm = fmaxf(cm, __shfl_xor(cm, 8, 64));
    cm = fmaxf(cm, __shfl_xor(cm, 16, 64));
    cm = fmaxf(cm, __shfl_xor(cm, 32, 64));
    float Mn = fmaxf(M, cm);
    float sc = __expf(M - Mn);   // 0 on first chunk (M=-1e30)
    float w = __expf(lg - Mn);   // 0 for inactive lanes / cl==7
    M = Mn;
    ssum = ssum * sc + w;
    alpha_s[wid][eo * 8 + cl] = w;
    float s0 = __shfl(sc, 0, 64), s1 = __shfl(sc, 1, 64);
    float s2 = __shfl(sc, 2, 64), s3 = __shfl(sc, 3, 64);
    float s4 = __shfl(sc, 4, 64), s5 = __shfl(sc, 5, 64);
    float s6 = __shfl(sc, 6, 64);
    o0 *= s0; o1 *= s1; o2 *= s2; o3 *= s3; o4 *= s4; o5 *= s5; o6 *= s6;

    // ---- phase B: weighted accumulation (xl rows L1-hot from phase A)
    for (int t = 0; t < lim; ++t) {
      int s = __shfl(src, t * 8, 64);
      uint4 xv = *(const uint4*)(xlt + (size_t)s * HCP + (size_t)lane * 8);
      float4 aA = *(const float4*)&alpha_s[wid][t * 8];
      float4 aB = *(const float4*)&alpha_s[wid][t * 8 + 4];
      o0 += aA.x * bf_lo(xv.x);
      o1 += aA.y * bf_hi(xv.x);
      o2 += aA.z * bf_lo(xv.y);
      o3 += aA.w * bf_hi(xv.y);
      o4 += aB.x * bf_lo(xv.z);
      o5 += aB.y * bf_hi(xv.z);
      o6 += aB.z * bf_lo(xv.w);
    }
  }

  // merge ssum over eo groups (all share final M)
  ssum += __shfl_xor(ssum, 8, 64);
  ssum += __shfl_xor(ssum, 16, 64);
  ssum += __shfl_xor(ssum, 32, 64);
  float rinv = 1.0f / (ssum + 1e-16f);
  float r0 = __shfl(rinv, 0, 64), r1 = __shfl(rinv, 1, 64);
  float r2 = __shfl(rinv, 2, 64), r3 = __shfl(rinv, 3, 64);
  float r4 = __shfl(rinv, 4, 64), r5 = __shfl(rinv, 5, 64);
  float r6 = __shfl(rinv, 6, 64);
  float accv = o0 * r0 + o1 * r1 + o2 * r2 + o3 * r3 + o4 * r4 + o5 * r5 + o6 * r6;
  float v = accv * (1.0f / 7.0f) + cbias[lane];
  hout[(size_t)n * 64 + lane] =
      __bfloat16_as_short(__float2bfloat16(fmaxf(v, 0.f)));
}

// ---------------------------------------------------------------------------
// Output MLP 64->32->16->9 + log_softmax, wave per node, 4 nodes per block.
// ---------------------------------------------------------------------------
__global__ __launch_bounds__(256) void out_mlp_kernel(
    const short* __restrict__ h, const float* __restrict__ V1,
    const float* __restrict__ c1, const float* __restrict__ V2,
    const float* __restrict__ c2, const float* __restrict__ V3,
    const float* __restrict__ c3, float* __restrict__ out) {
  __shared__ float hb[4][64], r1[4][32], r2[4][16], z3[4][9];
  int wid = threadIdx.x >> 6;
  int t = threadIdx.x & 63;
  int n = blockIdx.x * 4 + wid;
  hb[wid][t] =
      __uint_as_float(((unsigned)((const unsigned short*)h)[(size_t)n * 64 + t]) << 16);
  __syncthreads();
  if (t < 32) {
    float a = c1[t];
    #pragma unroll
    for (int k = 0; k < 64; ++k) a += hb[wid][k] * V1[k * 32 + t];
    r1[wid][t] = fmaxf(a, 0.f);
  }
  __syncthreads();
  if (t < 16) {
    float a = c2[t];
    #pragma unroll
    for (int k = 0; k < 32; ++k) a += r1[wid][k] * V2[k * 16 + t];
    r2[wid][t] = fmaxf(a, 0.f);
  }
  __syncthreads();
  if (t < 9) {
    float a = c3[t];
    #pragma unroll
    for (int k = 0; k < 16; ++k) a += r2[wid][k] * V3[k * 9 + t];
    z3[wid][t] = a;
  }
  __syncthreads();
  if (t < 9) {
    float mx = z3[wid][0];
    #pragma unroll
    for (int k = 1; k < 9; ++k) mx = fmaxf(mx, z3[wid][k]);
    float s = 0.f;
    #pragma unroll
    for (int k = 0; k < 9; ++k) s += __expf(z3[wid][k] - mx);
    out[(size_t)n * 9 + t] = z3[wid][t] - mx - logf(s);
  }
}

// ---------------------------------------------------------------------------
extern "C" void kernel_launch(void* const* d_in, const int* in_sizes, int n_in,
                              void* d_out, int out_size, void* d_ws, size_t ws_size,
                              hipStream_t stream) {
  const float* x   = (const float*)d_in[0];
  const int*   ei  = (const int*)d_in[1];
  const float* W1  = (const float*)d_in[2];
  const float* b1  = (const float*)d_in[3];
  const float* W2  = (const float*)d_in[4];
  const float* b2  = (const float*)d_in[5];
  const float* W3  = (const float*)d_in[6];
  const float* b3  = (const float*)d_in[7];
  const float* Wl  = (const float*)d_in[8];
  const float* bl  = (const float*)d_in[9];
  const float* Wr  = (const float*)d_in[10];
  const float* att = (const float*)d_in[11];
  const float* cb  = (const float*)d_in[12];
  const float* V1  = (const float*)d_in[13];
  const float* c1  = (const float*)d_in[14];
  const float* V2  = (const float*)d_in[15];
  const float* c2  = (const float*)d_in[16];
  const float* V3  = (const float*)d_in[17];
  const float* c3  = (const float*)d_in[18];
  float* out = (float*)d_out;

  char* ws = (char*)d_ws;
  size_t off = 0;
  auto alloc = [&](size_t bytes) {
    void* p = ws + off;
    off = (off + bytes + 255) & ~(size_t)255;
    return p;
  };
  // region0 (reused): xb (20.5MB) -> h2 -> xlt [N][1024] shorts
  char* region0 = (char*)alloc((size_t)NNODES * 1024 * 2 + 1024);
  short* xb  = (short*)region0;
  short* h2  = (short*)region0;
  short* xlt = (short*)region0;
  // region1 (reused): h1 (10.2MB) -> hA/hB
  char* region1 = (char*)alloc((size_t)NNODES * 512 * 2 + 1024);
  short* h1 = (short*)region1;
  short* hA = (short*)region1;
  short* hB = hA + (size_t)NNODES * 64;
  // persistent
  short* W1t = (short*)alloc((size_t)512 * 1024 * 2);
  short* W2t = (short*)alloc((size_t)256 * 512 * 2);
  short* W3t = (short*)alloc((size_t)64 * 256 * 2);
  short* Wgt = (short*)alloc((size_t)5 * HCP * 64 * 2);
  float* bg  = (float*)alloc((size_t)5 * HCP * 4);
  int* cnt       = (int*)alloc((size_t)NNODES * 4);
  int* row_start = (int*)alloc((size_t)(NNODES + 1) * 4);
  int* cursor    = (int*)alloc((size_t)NNODES * 4);
  int* csr_src   = (int*)alloc((size_t)ETOT * 4);

  // ---- pack / convert
  convert_f32_bf16<<<(NNODES * 1024 / 4 + 255) / 256, 256, 0, stream>>>(
      x, xb, NNODES * 1024 / 4);
  transpose_bf16<<<(1024 * 512 + 255) / 256, 256, 0, stream>>>(W1, W1t, 1024, 512);
  transpose_bf16<<<(512 * 256 + 255) / 256, 256, 0, stream>>>(W2, W2t, 512, 256);
  transpose_bf16<<<(256 * 64 + 255) / 256, 256, 0, stream>>>(W3, W3t, 256, 64);
  pack_gat<<<(5 * HCP * 64 + 255) / 256, 256, 0, stream>>>(Wl, Wr, bl, Wgt, bg);

  // ---- CSR build (self-loops included)
  init_cnt<<<(NNODES + 255) / 256, 256, 0, stream>>>(cnt);
  hist_kernel<<<(NEDGES + 255) / 256, 256, 0, stream>>>(ei, cnt);
  scan_kernel<<<1, 1024, 0, stream>>>(cnt, row_start, cursor);
  scatter_self<<<(NNODES + 255) / 256, 256, 0, stream>>>(cursor, csr_src);
  scatter_kernel<<<(NEDGES + 255) / 256, 256, 0, stream>>>(ei, cursor, csr_src);

  // ---- input MLP (bf16 MFMA)
  mfma_gemm<64, 128, 1><<<dim3(157, 4), 256, 0, stream>>>(
      xb, W1t, b1, h1, NNODES, 1024, 512);
  mfma_gemm<64, 128, 1><<<dim3(157, 2), 256, 0, stream>>>(
      h1, W2t, b2, h2, NNODES, 512, 256);
  mfma_gemm<64, 64, 1><<<dim3(157, 1), 256, 0, stream>>>(
      h2, W3t, b3, hA, NNODES, 256, 64);

  // ---- 5 GATv2 layers (GEMM + fused attention/aggregation)
  short* hcur = hA;
  short* hnext = hB;
  for (int layer = 0; layer < 5; ++layer) {
    mfma_gemm<128, 128, 0><<<dim3(79, 8), 256, 0, stream>>>(
        hcur, Wgt + (size_t)layer * HCP * 64, bg + (size_t)layer * HCP, xlt,
        NNODES, 64, HCP);
    gat_fused_kernel<<<2500, 256, 0, stream>>>(
        xlt, att + (size_t)layer * HC, cb + (size_t)layer * 64,
        row_start, csr_src, hnext);
    short* tmp = hcur; hcur = hnext; hnext = tmp;
  }

  // ---- output MLP + log_softmax
  out_mlp_kernel<<<2500, 256, 0, stream>>>(hcur, V1, c1, V2, c2, V3, c3, out);
}

// Round 7
// 579.752 us; speedup vs baseline: 1.1413x; 1.1413x over previous
//
#include <hip/hip_runtime.h>
#include <hip/hip_bf16.h>
#include <math.h>

#define NNODES 10000
#define NEDGES 160000
#define ETOT (NEDGES + NNODES)  // edges + self-loops
#define HEADS 7
#define CH 64
#define HC 448    // HEADS*CH
#define HCP 1024  // padded fused width: [xl 512 | xr 512], slot = half*512+c*8+h

typedef __attribute__((ext_vector_type(8))) short short8;
typedef __attribute__((ext_vector_type(4))) float floatx4;

__device__ __forceinline__ float bf_lo(unsigned u) {
  return __uint_as_float(u << 16);
}
__device__ __forceinline__ float bf_hi(unsigned u) {
  return __uint_as_float(u & 0xffff0000u);
}

// ---------------------------------------------------------------------------
// Conversion / packing kernels
// ---------------------------------------------------------------------------
__global__ __launch_bounds__(256) void convert_f32_bf16(
    const float* __restrict__ in, short* __restrict__ out, int n4) {
  int i = blockIdx.x * 256 + threadIdx.x;
  if (i < n4) {
    float4 v = *(const float4*)&in[(size_t)i * 4];
    short4 o;
    o.x = __bfloat16_as_short(__float2bfloat16(v.x));
    o.y = __bfloat16_as_short(__float2bfloat16(v.y));
    o.z = __bfloat16_as_short(__float2bfloat16(v.z));
    o.w = __bfloat16_as_short(__float2bfloat16(v.w));
    *(short4*)&out[(size_t)i * 4] = o;
  }
}

__global__ __launch_bounds__(256) void transpose_bf16(
    const float* __restrict__ in, short* __restrict__ out, int K, int N) {
  int idx = blockIdx.x * 256 + threadIdx.x;
  if (idx < K * N) {
    int n = idx / K, k = idx % K;
    out[idx] = __bfloat16_as_short(__float2bfloat16(in[(size_t)k * N + n]));
  }
}

// Wgt[l][col'][k], col' = half*512 + c*8 + h (h==7 -> zero pad). bg likewise.
__global__ __launch_bounds__(256) void pack_gat(
    const float* __restrict__ Wl, const float* __restrict__ Wr,
    const float* __restrict__ bl, short* __restrict__ Wgt,
    float* __restrict__ bg) {
  int idx = blockIdx.x * 256 + threadIdx.x;
  if (idx < 5 * HCP * 64) {
    int l = idx / (HCP * 64);
    int rem = idx % (HCP * 64);
    int col = rem / 64, k = rem % 64;
    int half = col >> 9;
    int within = col & 511;
    int c = within >> 3, h = within & 7;
    float v = 0.f;
    if (h < 7) {
      const float* W = half ? Wr : Wl;
      v = W[((size_t)l * 64 + k) * HC + h * 64 + c];
    }
    Wgt[idx] = __bfloat16_as_short(__float2bfloat16(v));
  }
  if (idx < 5 * HCP) {
    int l = idx >> 10, col = idx & 1023;
    int half = col >> 9, within = col & 511;
    int c = within >> 3, h = within & 7;
    bg[idx] = (!half && h < 7) ? bl[(size_t)l * HC + h * 64 + c] : 0.f;
  }
}

// ---------------------------------------------------------------------------
// MFMA bf16 GEMM: C = act(A @ Bt^T + bias), bf16 row-major out.
// ---------------------------------------------------------------------------
template <int BM, int BN, int RELU>
__global__ __launch_bounds__(256) void mfma_gemm(
    const short* __restrict__ A, const short* __restrict__ Bt,
    const float* __restrict__ bias, short* __restrict__ C,
    int M, int K, int Nc) {
  __shared__ short As[BM * 64];
  __shared__ short Bs[BN * 64];
  constexpr int MI = BM / 32;
  constexpr int NJ = BN / 32;
  int tid = threadIdx.x;
  int lane = tid & 63, wave = tid >> 6;
  int wm = wave >> 1, wn = wave & 1;
  int row0 = blockIdx.x * BM, col0 = blockIdx.y * BN;
  floatx4 acc[MI][NJ] = {};

  for (int k0 = 0; k0 < K; k0 += 64) {
    #pragma unroll
    for (int i = 0; i < BM / 32; ++i) {
      int c = i * 4 + wave;
      int r = c * 8 + (lane >> 3);
      int k = (lane & 7) * 8;
      int grow = row0 + r;
      if (grow >= M) grow = M - 1;
      __builtin_amdgcn_global_load_lds(
          (const __attribute__((address_space(1))) void*)(A + (size_t)grow * K + k0 + k),
          (__attribute__((address_space(3))) void*)(As + c * 512), 16, 0, 0);
    }
    #pragma unroll
    for (int i = 0; i < BN / 32; ++i) {
      int c = i * 4 + wave;
      int r = c * 8 + (lane >> 3);
      int k = (lane & 7) * 8;
      int gcol = col0 + r;
      if (gcol >= Nc) gcol = Nc - 1;
      __builtin_amdgcn_global_load_lds(
          (const __attribute__((address_space(1))) void*)(Bt + (size_t)gcol * K + k0 + k),
          (__attribute__((address_space(3))) void*)(Bs + c * 512), 16, 0, 0);
    }
    __syncthreads();
    int lr = lane & 15, lq = lane >> 4;
    #pragma unroll
    for (int kk = 0; kk < 64; kk += 32) {
      short8 af[MI], bf[NJ];
      #pragma unroll
      for (int i = 0; i < MI; ++i)
        af[i] = *(const short8*)&As[(wm * (BM / 2) + i * 16 + lr) * 64 + kk + lq * 8];
      #pragma unroll
      for (int j = 0; j < NJ; ++j)
        bf[j] = *(const short8*)&Bs[(wn * (BN / 2) + j * 16 + lr) * 64 + kk + lq * 8];
      #pragma unroll
      for (int i = 0; i < MI; ++i)
        #pragma unroll
        for (int j = 0; j < NJ; ++j)
          acc[i][j] = __builtin_amdgcn_mfma_f32_16x16x32_bf16(
              af[i], bf[j], acc[i][j], 0, 0, 0);
    }
    __syncthreads();
  }

  int lr = lane & 15, lq = lane >> 4;
  #pragma unroll
  for (int j = 0; j < NJ; ++j) {
    int col = col0 + wn * (BN / 2) + j * 16 + lr;
    float bj = bias ? bias[col] : 0.f;
    #pragma unroll
    for (int i = 0; i < MI; ++i) {
      int rbase = row0 + wm * (BM / 2) + i * 16 + lq * 4;
      #pragma unroll
      for (int r = 0; r < 4; ++r) {
        int row = rbase + r;
        if (row < M) {
          float v = acc[i][j][r] + bj;
          if (RELU) v = fmaxf(v, 0.f);
          C[(size_t)row * Nc + col] = __bfloat16_as_short(__float2bfloat16(v));
        }
      }
    }
  }
}

// ---------------------------------------------------------------------------
// CSR build (dst-grouped, self-loops included).
// ---------------------------------------------------------------------------
__global__ void init_cnt(int* __restrict__ cnt) {
  int i = blockIdx.x * 256 + threadIdx.x;
  if (i < NNODES) cnt[i] = 1;  // self-loop
}

__global__ void hist_kernel(const int* __restrict__ ei, int* __restrict__ cnt) {
  int e = blockIdx.x * 256 + threadIdx.x;
  if (e < NEDGES) atomicAdd(&cnt[ei[NEDGES + e]], 1);
}

// single-block shuffle-based scan
__global__ __launch_bounds__(1024) void scan_kernel(
    const int* __restrict__ cnt, int* __restrict__ row_start,
    int* __restrict__ cursor) {
  __shared__ int wsum[16];
  int t = threadIdx.x;
  int lane = t & 63, w = t >> 6;
  int base = t * 10;
  int v[10], s = 0;
  #pragma unroll
  for (int i = 0; i < 10; ++i) {
    v[i] = (base + i < NNODES) ? cnt[base + i] : 0;
    s += v[i];
  }
  int incl = s;
  #pragma unroll
  for (int off = 1; off < 64; off <<= 1) {
    int o = __shfl_up(incl, off, 64);
    if (lane >= off) incl += o;
  }
  if (lane == 63) wsum[w] = incl;
  __syncthreads();
  if (w == 0) {
    int wv = (lane < 16) ? wsum[lane] : 0;
    #pragma unroll
    for (int off = 1; off < 16; off <<= 1) {
      int o = __shfl_up(wv, off, 64);
      if (lane >= off) wv += o;
    }
    if (lane < 16) wsum[lane] = wv;
  }
  __syncthreads();
  int woff = (w > 0) ? wsum[w - 1] : 0;
  int excl = woff + incl - s;
  #pragma unroll
  for (int i = 0; i < 10; ++i) {
    if (base + i < NNODES) {
      row_start[base + i] = excl;
      cursor[base + i] = excl;
    }
    excl += v[i];
  }
  if (t == 1023) row_start[NNODES] = wsum[15];
}

__global__ void scatter_self(int* __restrict__ cursor,
                             int* __restrict__ csr_src,
                             int* __restrict__ csr_dst) {
  int n = blockIdx.x * 256 + threadIdx.x;
  if (n < NNODES) {
    int pos = atomicAdd(&cursor[n], 1);
    csr_src[pos] = n;
    csr_dst[pos] = n;
  }
}

__global__ void scatter_kernel(const int* __restrict__ ei,
                               int* __restrict__ cursor,
                               int* __restrict__ csr_src,
                               int* __restrict__ csr_dst) {
  int e = blockIdx.x * 256 + threadIdx.x;
  if (e < NEDGES) {
    int d = ei[NEDGES + e];
    int pos = atomicAdd(&cursor[d], 1);
    csr_src[pos] = ei[e];
    csr_dst[pos] = d;
  }
}

// ---------------------------------------------------------------------------
// Pass A: edge weights w = exp(logit), 8 lanes per edge on xlt[n][c][8].
// Max-free softmax: fp32 exp range vastly exceeds logit magnitudes here.
// ---------------------------------------------------------------------------
__global__ __launch_bounds__(256) void edge_logits_kernel(
    const short* __restrict__ xlt, const float* __restrict__ att,
    const int* __restrict__ csr_src, const int* __restrict__ csr_dst,
    float* __restrict__ wbuf) {
  __shared__ float att_s[512];  // att_t[c][h]
  for (int i = threadIdx.x; i < 512; i += 256) {
    int c = i >> 3, h = i & 7;
    att_s[i] = (h < 7) ? att[h * 64 + c] : 0.f;
  }
  __syncthreads();
  int lane = threadIdx.x & 63;
  int wid = threadIdx.x >> 6;
  int eo = lane >> 3, cl = lane & 7;
  int e = (blockIdx.x * 4 + wid) * 8 + eo;
  int ec = (e < ETOT) ? e : (ETOT - 1);
  int s = csr_src[ec], d = csr_dst[ec];
  const uint4* xlp = (const uint4*)(xlt + (size_t)s * HCP);
  const uint4* xrp = (const uint4*)(xlt + (size_t)d * HCP + 512);
  float acc[7];
  #pragma unroll
  for (int h = 0; h < 7; ++h) acc[h] = 0.f;
  #pragma unroll
  for (int q = 0; q < 8; ++q) {
    int c = q * 8 + cl;
    uint4 a = xlp[c];
    uint4 b = xrp[c];
    float4 t0 = *(const float4*)&att_s[c * 8];
    float4 t1 = *(const float4*)&att_s[c * 8 + 4];
    float e0 = bf_lo(a.x) + bf_lo(b.x);
    float e1 = bf_hi(a.x) + bf_hi(b.x);
    float e2 = bf_lo(a.y) + bf_lo(b.y);
    float e3 = bf_hi(a.y) + bf_hi(b.y);
    float e4 = bf_lo(a.z) + bf_lo(b.z);
    float e5 = bf_hi(a.z) + bf_hi(b.z);
    float e6 = bf_lo(a.w) + bf_lo(b.w);
    e0 = fmaxf(e0, 0.2f * e0); e1 = fmaxf(e1, 0.2f * e1);
    e2 = fmaxf(e2, 0.2f * e2); e3 = fmaxf(e3, 0.2f * e3);
    e4 = fmaxf(e4, 0.2f * e4); e5 = fmaxf(e5, 0.2f * e5);
    e6 = fmaxf(e6, 0.2f * e6);
    acc[0] += t0.x * e0; acc[1] += t0.y * e1;
    acc[2] += t0.z * e2; acc[3] += t0.w * e3;
    acc[4] += t1.x * e4; acc[5] += t1.y * e5;
    acc[6] += t1.z * e6;
  }
  #pragma unroll
  for (int h = 0; h < 7; ++h) {
    acc[h] += __shfl_xor(acc[h], 1, 64);
    acc[h] += __shfl_xor(acc[h], 2, 64);
    acc[h] += __shfl_xor(acc[h], 4, 64);
  }
  float res = 0.f;
  #pragma unroll
  for (int h = 0; h < 7; ++h) res = (cl == h) ? acc[h] : res;
  float wv = (cl < 7) ? __expf(res) : 0.f;
  if (e < ETOT) wbuf[(size_t)e * 8 + cl] = wv;  // 256B coalesced per wave
}

// ---------------------------------------------------------------------------
// Pass B: single-pass aggregation. Wave per node, lane = channel.
// out[h] = sum_e w[e][h]*xl[src_e]; denom[h] = sum_e w[e][h]; divide at end.
// ---------------------------------------------------------------------------
__global__ __launch_bounds__(256) void gat_agg2_kernel(
    const short* __restrict__ xlt, const float* __restrict__ wbuf,
    const float* __restrict__ cbias, const int* __restrict__ row_start,
    const int* __restrict__ csr_src, short* __restrict__ hout) {
  int lane = threadIdx.x & 63;
  int wid = threadIdx.x >> 6;
  int n = blockIdx.x * 4 + wid;
  if (n >= NNODES) return;
  int beg = row_start[n], end = row_start[n + 1];

  float o0 = 0.f, o1 = 0.f, o2 = 0.f, o3 = 0.f, o4 = 0.f, o5 = 0.f, o6 = 0.f;
  float s0 = 0.f, s1 = 0.f, s2 = 0.f, s3 = 0.f, s4 = 0.f, s5 = 0.f, s6 = 0.f;
  #pragma unroll 2
  for (int e = beg; e < end; ++e) {
    int src = csr_src[e];
    float4 wa = *(const float4*)&wbuf[(size_t)e * 8];      // uniform
    float4 wb = *(const float4*)&wbuf[(size_t)e * 8 + 4];  // uniform
    uint4 xv = *(const uint4*)(xlt + (size_t)src * HCP + (size_t)lane * 8);
    o0 += wa.x * bf_lo(xv.x);
    o1 += wa.y * bf_hi(xv.x);
    o2 += wa.z * bf_lo(xv.y);
    o3 += wa.w * bf_hi(xv.y);
    o4 += wb.x * bf_lo(xv.z);
    o5 += wb.y * bf_hi(xv.z);
    o6 += wb.z * bf_lo(xv.w);
    s0 += wa.x; s1 += wa.y; s2 += wa.z; s3 += wa.w;
    s4 += wb.x; s5 += wb.y; s6 += wb.z;
  }

  float accv = o0 / (s0 + 1e-16f) + o1 / (s1 + 1e-16f) + o2 / (s2 + 1e-16f) +
               o3 / (s3 + 1e-16f) + o4 / (s4 + 1e-16f) + o5 / (s5 + 1e-16f) +
               o6 / (s6 + 1e-16f);
  float v = accv * (1.0f / 7.0f) + cbias[lane];
  hout[(size_t)n * 64 + lane] =
      __bfloat16_as_short(__float2bfloat16(fmaxf(v, 0.f)));
}

// ---------------------------------------------------------------------------
// Output MLP 64->32->16->9 + log_softmax, wave per node, 4 nodes per block.
// ---------------------------------------------------------------------------
__global__ __launch_bounds__(256) void out_mlp_kernel(
    const short* __restrict__ h, const float* __restrict__ V1,
    const float* __restrict__ c1, const float* __restrict__ V2,
    const float* __restrict__ c2, const float* __restrict__ V3,
    const float* __restrict__ c3, float* __restrict__ out) {
  __shared__ float hb[4][64], r1[4][32], r2[4][16], z3[4][9];
  int wid = threadIdx.x >> 6;
  int t = threadIdx.x & 63;
  int n = blockIdx.x * 4 + wid;
  hb[wid][t] =
      __uint_as_float(((unsigned)((const unsigned short*)h)[(size_t)n * 64 + t]) << 16);
  __syncthreads();
  if (t < 32) {
    float a = c1[t];
    #pragma unroll
    for (int k = 0; k < 64; ++k) a += hb[wid][k] * V1[k * 32 + t];
    r1[wid][t] = fmaxf(a, 0.f);
  }
  __syncthreads();
  if (t < 16) {
    float a = c2[t];
    #pragma unroll
    for (int k = 0; k < 32; ++k) a += r1[wid][k] * V2[k * 16 + t];
    r2[wid][t] = fmaxf(a, 0.f);
  }
  __syncthreads();
  if (t < 9) {
    float a = c3[t];
    #pragma unroll
    for (int k = 0; k < 16; ++k) a += r2[wid][k] * V3[k * 9 + t];
    z3[wid][t] = a;
  }
  __syncthreads();
  if (t < 9) {
    float mx = z3[wid][0];
    #pragma unroll
    for (int k = 1; k < 9; ++k) mx = fmaxf(mx, z3[wid][k]);
    float s = 0.f;
    #pragma unroll
    for (int k = 0; k < 9; ++k) s += __expf(z3[wid][k] - mx);
    out[(size_t)n * 9 + t] = z3[wid][t] - mx - logf(s);
  }
}

// ---------------------------------------------------------------------------
extern "C" void kernel_launch(void* const* d_in, const int* in_sizes, int n_in,
                              void* d_out, int out_size, void* d_ws, size_t ws_size,
                              hipStream_t stream) {
  const float* x   = (const float*)d_in[0];
  const int*   ei  = (const int*)d_in[1];
  const float* W1  = (const float*)d_in[2];
  const float* b1  = (const float*)d_in[3];
  const float* W2  = (const float*)d_in[4];
  const float* b2  = (const float*)d_in[5];
  const float* W3  = (const float*)d_in[6];
  const float* b3  = (const float*)d_in[7];
  const float* Wl  = (const float*)d_in[8];
  const float* bl  = (const float*)d_in[9];
  const float* Wr  = (const float*)d_in[10];
  const float* att = (const float*)d_in[11];
  const float* cb  = (const float*)d_in[12];
  const float* V1  = (const float*)d_in[13];
  const float* c1  = (const float*)d_in[14];
  const float* V2  = (const float*)d_in[15];
  const float* c2  = (const float*)d_in[16];
  const float* V3  = (const float*)d_in[17];
  const float* c3  = (const float*)d_in[18];
  float* out = (float*)d_out;

  char* ws = (char*)d_ws;
  size_t off = 0;
  auto alloc = [&](size_t bytes) {
    void* p = ws + off;
    off = (off + bytes + 255) & ~(size_t)255;
    return p;
  };
  // region0 (reused): xb (20.5MB) -> h2 -> xlt [N][1024] shorts
  char* region0 = (char*)alloc((size_t)NNODES * 1024 * 2 + 1024);
  short* xb  = (short*)region0;
  short* h2  = (short*)region0;
  short* xlt = (short*)region0;
  // region1 (reused): h1 (10.2MB) -> hA/hB
  char* region1 = (char*)alloc((size_t)NNODES * 512 * 2 + 1024);
  short* h1 = (short*)region1;
  short* hA = (short*)region1;
  short* hB = hA + (size_t)NNODES * 64;
  // persistent
  short* W1t = (short*)alloc((size_t)512 * 1024 * 2);
  short* W2t = (short*)alloc((size_t)256 * 512 * 2);
  short* W3t = (short*)alloc((size_t)64 * 256 * 2);
  short* Wgt = (short*)alloc((size_t)5 * HCP * 64 * 2);
  float* bg  = (float*)alloc((size_t)5 * HCP * 4);
  int* cnt       = (int*)alloc((size_t)NNODES * 4);
  int* row_start = (int*)alloc((size_t)(NNODES + 1) * 4);
  int* cursor    = (int*)alloc((size_t)NNODES * 4);
  int* csr_src   = (int*)alloc((size_t)ETOT * 4);
  int* csr_dst   = (int*)alloc((size_t)ETOT * 4);
  float* wbuf    = (float*)alloc((size_t)ETOT * 8 * 4);

  // ---- pack / convert
  convert_f32_bf16<<<(NNODES * 1024 / 4 + 255) / 256, 256, 0, stream>>>(
      x, xb, NNODES * 1024 / 4);
  transpose_bf16<<<(1024 * 512 + 255) / 256, 256, 0, stream>>>(W1, W1t, 1024, 512);
  transpose_bf16<<<(512 * 256 + 255) / 256, 256, 0, stream>>>(W2, W2t, 512, 256);
  transpose_bf16<<<(256 * 64 + 255) / 256, 256, 0, stream>>>(W3, W3t, 256, 64);
  pack_gat<<<(5 * HCP * 64 + 255) / 256, 256, 0, stream>>>(Wl, Wr, bl, Wgt, bg);

  // ---- CSR build (self-loops included)
  init_cnt<<<(NNODES + 255) / 256, 256, 0, stream>>>(cnt);
  hist_kernel<<<(NEDGES + 255) / 256, 256, 0, stream>>>(ei, cnt);
  scan_kernel<<<1, 1024, 0, stream>>>(cnt, row_start, cursor);
  scatter_self<<<(NNODES + 255) / 256, 256, 0, stream>>>(cursor, csr_src, csr_dst);
  scatter_kernel<<<(NEDGES + 255) / 256, 256, 0, stream>>>(ei, cursor, csr_src, csr_dst);

  // ---- input MLP (bf16 MFMA)
  mfma_gemm<64, 128, 1><<<dim3(157, 4), 256, 0, stream>>>(
      xb, W1t, b1, h1, NNODES, 1024, 512);
  mfma_gemm<64, 128, 1><<<dim3(157, 2), 256, 0, stream>>>(
      h1, W2t, b2, h2, NNODES, 512, 256);
  mfma_gemm<64, 64, 1><<<dim3(157, 1), 256, 0, stream>>>(
      h2, W3t, b3, hA, NNODES, 256, 64);

  // ---- 5 GATv2 layers
  short* hcur = hA;
  short* hnext = hB;
  for (int layer = 0; layer < 5; ++layer) {
    mfma_gemm<128, 128, 0><<<dim3(79, 8), 256, 0, stream>>>(
        hcur, Wgt + (size_t)layer * HCP * 64, bg + (size_t)layer * HCP, xlt,
        NNODES, 64, HCP);
    edge_logits_kernel<<<(ETOT + 31) / 32, 256, 0, stream>>>(
        xlt, att + (size_t)layer * HC, csr_src, csr_dst, wbuf);
    gat_agg2_kernel<<<2500, 256, 0, stream>>>(
        xlt, wbuf, cb + (size_t)layer * 64, row_start, csr_src, hnext);
    short* tmp = hcur; hcur = hnext; hnext = tmp;
  }

  // ---- output MLP + log_softmax
  out_mlp_kernel<<<2500, 256, 0, stream>>>(hcur, V1, c1, V2, c2, V3, c3, out);
}

// Round 8
// 551.713 us; speedup vs baseline: 1.1993x; 1.0508x over previous
//
#include <hip/hip_runtime.h>
#include <hip/hip_bf16.h>
#include <math.h>

#define NNODES 10000
#define NEDGES 160000
#define ETOT (NEDGES + NNODES)  // edges + self-loops
#define HEADS 7
#define CH 64
#define HC 448    // HEADS*CH
#define HCP 1024  // padded fused width: [xl 512 | xr 512], slot = half*512+c*8+h

typedef __attribute__((ext_vector_type(8))) short short8;
typedef __attribute__((ext_vector_type(4))) float floatx4;

__device__ __forceinline__ float bf_lo(unsigned u) {
  return __uint_as_float(u << 16);
}
__device__ __forceinline__ float bf_hi(unsigned u) {
  return __uint_as_float(u & 0xffff0000u);
}
__device__ __forceinline__ short f2bf(float v) {
  return __bfloat16_as_short(__float2bfloat16(v));
}

// ---------------------------------------------------------------------------
// Fused prep: x->bf16, W1/W2/W3 transpose->bf16, GAT weight pack, cnt init.
// One grid-stride task id per element.
// ---------------------------------------------------------------------------
#define P0 2560000                // convert groups (4 floats each)
#define P1 (P0 + 512 * 1024)      // W1t entries
#define P2 (P1 + 256 * 512)       // W2t
#define P3 (P2 + 64 * 256)        // W3t
#define P4 (P3 + 5 * HCP * 64)    // Wgt
#define P5 (P4 + 5 * HCP)         // bg
#define P6 (P5 + NNODES)          // cnt init
#define PTOT P6

__global__ __launch_bounds__(256) void prep_kernel(
    const float* __restrict__ x, short* __restrict__ xb,
    const float* __restrict__ W1, short* __restrict__ W1t,
    const float* __restrict__ W2, short* __restrict__ W2t,
    const float* __restrict__ W3, short* __restrict__ W3t,
    const float* __restrict__ Wl, const float* __restrict__ Wr,
    const float* __restrict__ bl, short* __restrict__ Wgt,
    float* __restrict__ bg, int* __restrict__ cnt) {
  int idx = blockIdx.x * 256 + threadIdx.x;
  if (idx < P0) {
    float4 v = *(const float4*)&x[(size_t)idx * 4];
    short4 o;
    o.x = f2bf(v.x); o.y = f2bf(v.y); o.z = f2bf(v.z); o.w = f2bf(v.w);
    *(short4*)&xb[(size_t)idx * 4] = o;
  } else if (idx < P1) {
    int i = idx - P0;               // W1: K=1024, N=512
    int n = i / 1024, k = i % 1024;
    W1t[i] = f2bf(W1[(size_t)k * 512 + n]);
  } else if (idx < P2) {
    int i = idx - P1;               // W2: K=512, N=256
    int n = i / 512, k = i % 512;
    W2t[i] = f2bf(W2[(size_t)k * 256 + n]);
  } else if (idx < P3) {
    int i = idx - P2;               // W3: K=256, N=64
    int n = i / 256, k = i % 256;
    W3t[i] = f2bf(W3[(size_t)k * 64 + n]);
  } else if (idx < P4) {
    int i = idx - P3;               // Wgt[l][col'][k]
    int l = i / (HCP * 64);
    int rem = i % (HCP * 64);
    int col = rem / 64, k = rem % 64;
    int half = col >> 9;
    int within = col & 511;
    int c = within >> 3, h = within & 7;
    float v = 0.f;
    if (h < 7) {
      const float* W = half ? Wr : Wl;
      v = W[((size_t)l * 64 + k) * HC + h * 64 + c];
    }
    Wgt[i] = f2bf(v);
  } else if (idx < P5) {
    int i = idx - P4;
    int l = i >> 10, col = i & 1023;
    int half = col >> 9, within = col & 511;
    int c = within >> 3, h = within & 7;
    bg[i] = (!half && h < 7) ? bl[(size_t)l * HC + h * 64 + c] : 0.f;
  } else if (idx < P6) {
    cnt[idx - P5] = 1;  // self-loop
  }
}

// ---------------------------------------------------------------------------
// MFMA bf16 GEMM: C = act(A @ Bt^T + bias), bf16 row-major out.
// ---------------------------------------------------------------------------
template <int BM, int BN, int RELU>
__global__ __launch_bounds__(256) void mfma_gemm(
    const short* __restrict__ A, const short* __restrict__ Bt,
    const float* __restrict__ bias, short* __restrict__ C,
    int M, int K, int Nc) {
  __shared__ short As[BM * 64];
  __shared__ short Bs[BN * 64];
  constexpr int MI = BM / 32;
  constexpr int NJ = BN / 32;
  int tid = threadIdx.x;
  int lane = tid & 63, wave = tid >> 6;
  int wm = wave >> 1, wn = wave & 1;
  int row0 = blockIdx.x * BM, col0 = blockIdx.y * BN;
  floatx4 acc[MI][NJ] = {};

  for (int k0 = 0; k0 < K; k0 += 64) {
    #pragma unroll
    for (int i = 0; i < BM / 32; ++i) {
      int c = i * 4 + wave;
      int r = c * 8 + (lane >> 3);
      int k = (lane & 7) * 8;
      int grow = row0 + r;
      if (grow >= M) grow = M - 1;
      __builtin_amdgcn_global_load_lds(
          (const __attribute__((address_space(1))) void*)(A + (size_t)grow * K + k0 + k),
          (__attribute__((address_space(3))) void*)(As + c * 512), 16, 0, 0);
    }
    #pragma unroll
    for (int i = 0; i < BN / 32; ++i) {
      int c = i * 4 + wave;
      int r = c * 8 + (lane >> 3);
      int k = (lane & 7) * 8;
      int gcol = col0 + r;
      if (gcol >= Nc) gcol = Nc - 1;
      __builtin_amdgcn_global_load_lds(
          (const __attribute__((address_space(1))) void*)(Bt + (size_t)gcol * K + k0 + k),
          (__attribute__((address_space(3))) void*)(Bs + c * 512), 16, 0, 0);
    }
    __syncthreads();
    int lr = lane & 15, lq = lane >> 4;
    #pragma unroll
    for (int kk = 0; kk < 64; kk += 32) {
      short8 af[MI], bf[NJ];
      #pragma unroll
      for (int i = 0; i < MI; ++i)
        af[i] = *(const short8*)&As[(wm * (BM / 2) + i * 16 + lr) * 64 + kk + lq * 8];
      #pragma unroll
      for (int j = 0; j < NJ; ++j)
        bf[j] = *(const short8*)&Bs[(wn * (BN / 2) + j * 16 + lr) * 64 + kk + lq * 8];
      #pragma unroll
      for (int i = 0; i < MI; ++i)
        #pragma unroll
        for (int j = 0; j < NJ; ++j)
          acc[i][j] = __builtin_amdgcn_mfma_f32_16x16x32_bf16(
              af[i], bf[j], acc[i][j], 0, 0, 0);
    }
    __syncthreads();
  }

  int lr = lane & 15, lq = lane >> 4;
  #pragma unroll
  for (int j = 0; j < NJ; ++j) {
    int col = col0 + wn * (BN / 2) + j * 16 + lr;
    float bj = bias ? bias[col] : 0.f;
    #pragma unroll
    for (int i = 0; i < MI; ++i) {
      int rbase = row0 + wm * (BM / 2) + i * 16 + lq * 4;
      #pragma unroll
      for (int r = 0; r < 4; ++r) {
        int row = rbase + r;
        if (row < M) {
          float v = acc[i][j][r] + bj;
          if (RELU) v = fmaxf(v, 0.f);
          C[(size_t)row * Nc + col] = f2bf(v);
        }
      }
    }
  }
}

// ---------------------------------------------------------------------------
// CSR build (dst-grouped, self-loops included).
// ---------------------------------------------------------------------------
__global__ void hist_kernel(const int* __restrict__ ei, int* __restrict__ cnt) {
  int e = blockIdx.x * 256 + threadIdx.x;
  if (e < NEDGES) atomicAdd(&cnt[ei[NEDGES + e]], 1);
}

// single-block shuffle-based scan
__global__ __launch_bounds__(1024) void scan_kernel(
    const int* __restrict__ cnt, int* __restrict__ row_start,
    int* __restrict__ cursor) {
  __shared__ int wsum[16];
  int t = threadIdx.x;
  int lane = t & 63, w = t >> 6;
  int base = t * 10;
  int v[10], s = 0;
  #pragma unroll
  for (int i = 0; i < 10; ++i) {
    v[i] = (base + i < NNODES) ? cnt[base + i] : 0;
    s += v[i];
  }
  int incl = s;
  #pragma unroll
  for (int off = 1; off < 64; off <<= 1) {
    int o = __shfl_up(incl, off, 64);
    if (lane >= off) incl += o;
  }
  if (lane == 63) wsum[w] = incl;
  __syncthreads();
  if (w == 0) {
    int wv = (lane < 16) ? wsum[lane] : 0;
    #pragma unroll
    for (int off = 1; off < 16; off <<= 1) {
      int o = __shfl_up(wv, off, 64);
      if (lane >= off) wv += o;
    }
    if (lane < 16) wsum[lane] = wv;
  }
  __syncthreads();
  int woff = (w > 0) ? wsum[w - 1] : 0;
  int excl = woff + incl - s;
  #pragma unroll
  for (int i = 0; i < 10; ++i) {
    if (base + i < NNODES) {
      row_start[base + i] = excl;
      cursor[base + i] = excl;
    }
    excl += v[i];
  }
  if (t == 1023) row_start[NNODES] = wsum[15];
}

// merged scatter: t < NNODES -> self loop; else graph edge
__global__ void scatter_kernel(const int* __restrict__ ei,
                               int* __restrict__ cursor,
                               int* __restrict__ csr_src,
                               int* __restrict__ csr_dst) {
  int t = blockIdx.x * 256 + threadIdx.x;
  if (t < NNODES) {
    int pos = atomicAdd(&cursor[t], 1);
    csr_src[pos] = t;
    csr_dst[pos] = t;
  } else if (t < ETOT) {
    int e = t - NNODES;
    int d = ei[NEDGES + e];
    int pos = atomicAdd(&cursor[d], 1);
    csr_src[pos] = ei[e];
    csr_dst[pos] = d;
  }
}

// ---------------------------------------------------------------------------
// Pass A: edge weights w = exp(logit), 8 lanes per edge on xlt[n][c][8].
// Max-free softmax (fp32 exp range >> logit magnitudes here).
// ---------------------------------------------------------------------------
__global__ __launch_bounds__(256) void edge_logits_kernel(
    const short* __restrict__ xlt, const float* __restrict__ att,
    const int* __restrict__ csr_src, const int* __restrict__ csr_dst,
    float* __restrict__ wbuf) {
  __shared__ float att_s[512];  // att_t[c][h]
  for (int i = threadIdx.x; i < 512; i += 256) {
    int c = i >> 3, h = i & 7;
    att_s[i] = (h < 7) ? att[h * 64 + c] : 0.f;
  }
  __syncthreads();
  int lane = threadIdx.x & 63;
  int wid = threadIdx.x >> 6;
  int eo = lane >> 3, cl = lane & 7;
  int e = (blockIdx.x * 4 + wid) * 8 + eo;
  int ec = (e < ETOT) ? e : (ETOT - 1);
  int s = csr_src[ec], d = csr_dst[ec];
  const uint4* xlp = (const uint4*)(xlt + (size_t)s * HCP);
  const uint4* xrp = (const uint4*)(xlt + (size_t)d * HCP + 512);
  float acc[7];
  #pragma unroll
  for (int h = 0; h < 7; ++h) acc[h] = 0.f;
  #pragma unroll
  for (int q = 0; q < 8; ++q) {
    int c = q * 8 + cl;
    uint4 a = xlp[c];
    uint4 b = xrp[c];
    float4 t0 = *(const float4*)&att_s[c * 8];
    float4 t1 = *(const float4*)&att_s[c * 8 + 4];
    float e0 = bf_lo(a.x) + bf_lo(b.x);
    float e1 = bf_hi(a.x) + bf_hi(b.x);
    float e2 = bf_lo(a.y) + bf_lo(b.y);
    float e3 = bf_hi(a.y) + bf_hi(b.y);
    float e4 = bf_lo(a.z) + bf_lo(b.z);
    float e5 = bf_hi(a.z) + bf_hi(b.z);
    float e6 = bf_lo(a.w) + bf_lo(b.w);
    e0 = fmaxf(e0, 0.2f * e0); e1 = fmaxf(e1, 0.2f * e1);
    e2 = fmaxf(e2, 0.2f * e2); e3 = fmaxf(e3, 0.2f * e3);
    e4 = fmaxf(e4, 0.2f * e4); e5 = fmaxf(e5, 0.2f * e5);
    e6 = fmaxf(e6, 0.2f * e6);
    acc[0] += t0.x * e0; acc[1] += t0.y * e1;
    acc[2] += t0.z * e2; acc[3] += t0.w * e3;
    acc[4] += t1.x * e4; acc[5] += t1.y * e5;
    acc[6] += t1.z * e6;
  }
  #pragma unroll
  for (int h = 0; h < 7; ++h) {
    acc[h] += __shfl_xor(acc[h], 1, 64);
    acc[h] += __shfl_xor(acc[h], 2, 64);
    acc[h] += __shfl_xor(acc[h], 4, 64);
  }
  float res = 0.f;
  #pragma unroll
  for (int h = 0; h < 7; ++h) res = (cl == h) ? acc[h] : res;
  float wv = (cl < 7) ? __expf(res) : 0.f;
  if (e < ETOT) wbuf[(size_t)e * 8 + cl] = wv;  // 256B coalesced per wave
}

// ---------------------------------------------------------------------------
// Pass B: single-pass aggregation, TWO waves per node (stride-2 edge split),
// LDS merge. lane = channel. FINAL=1 additionally runs the output MLP
// 64->32->16->9 + log_softmax in-wave (no hout store).
// Grid: 5000 blocks x 256 thr = 2 nodes/block x 2 waves/node. No early
// returns (10000 nodes exactly) -> __syncthreads is uniform.
// ---------------------------------------------------------------------------
template <int FINAL>
__global__ __launch_bounds__(256) void gat_agg2_kernel(
    const short* __restrict__ xlt, const float* __restrict__ wbuf,
    const float* __restrict__ cbias, const int* __restrict__ row_start,
    const int* __restrict__ csr_src, short* __restrict__ hout,
    const float* __restrict__ V1, const float* __restrict__ c1,
    const float* __restrict__ V2, const float* __restrict__ c2,
    const float* __restrict__ V3, const float* __restrict__ c3,
    float* __restrict__ out) {
  __shared__ float part[2][14][64];  // odd-wave partials per node slot
  __shared__ float hb[2][64], r1[2][32], r2[2][16], z3[2][9];
  int lane = threadIdx.x & 63;
  int wv = threadIdx.x >> 6;  // 0..3
  int nw = wv >> 1;           // node slot 0..1
  int half = wv & 1;          // which edge half
  int n = blockIdx.x * 2 + nw;
  int beg = row_start[n], end = row_start[n + 1];

  float o0 = 0.f, o1 = 0.f, o2 = 0.f, o3 = 0.f, o4 = 0.f, o5 = 0.f, o6 = 0.f;
  float s0 = 0.f, s1 = 0.f, s2 = 0.f, s3 = 0.f, s4 = 0.f, s5 = 0.f, s6 = 0.f;
  #pragma unroll 2
  for (int e = beg + half; e < end; e += 2) {
    int src = csr_src[e];
    float4 wa = *(const float4*)&wbuf[(size_t)e * 8];      // uniform
    float4 wb = *(const float4*)&wbuf[(size_t)e * 8 + 4];  // uniform
    uint4 xv = *(const uint4*)(xlt + (size_t)src * HCP + (size_t)lane * 8);
    o0 += wa.x * bf_lo(xv.x);
    o1 += wa.y * bf_hi(xv.x);
    o2 += wa.z * bf_lo(xv.y);
    o3 += wa.w * bf_hi(xv.y);
    o4 += wb.x * bf_lo(xv.z);
    o5 += wb.y * bf_hi(xv.z);
    o6 += wb.z * bf_lo(xv.w);
    s0 += wa.x; s1 += wa.y; s2 += wa.z; s3 += wa.w;
    s4 += wb.x; s5 += wb.y; s6 += wb.z;
  }

  if (half == 1) {
    part[nw][0][lane] = o0;  part[nw][1][lane] = o1;
    part[nw][2][lane] = o2;  part[nw][3][lane] = o3;
    part[nw][4][lane] = o4;  part[nw][5][lane] = o5;
    part[nw][6][lane] = o6;
    part[nw][7][lane] = s0;  part[nw][8][lane] = s1;
    part[nw][9][lane] = s2;  part[nw][10][lane] = s3;
    part[nw][11][lane] = s4; part[nw][12][lane] = s5;
    part[nw][13][lane] = s6;
  }
  __syncthreads();
  if (half == 0) {
    o0 += part[nw][0][lane];  o1 += part[nw][1][lane];
    o2 += part[nw][2][lane];  o3 += part[nw][3][lane];
    o4 += part[nw][4][lane];  o5 += part[nw][5][lane];
    o6 += part[nw][6][lane];
    s0 += part[nw][7][lane];  s1 += part[nw][8][lane];
    s2 += part[nw][9][lane];  s3 += part[nw][10][lane];
    s4 += part[nw][11][lane]; s5 += part[nw][12][lane];
    s6 += part[nw][13][lane];
    float accv = o0 / (s0 + 1e-16f) + o1 / (s1 + 1e-16f) + o2 / (s2 + 1e-16f) +
                 o3 / (s3 + 1e-16f) + o4 / (s4 + 1e-16f) + o5 / (s5 + 1e-16f) +
                 o6 / (s6 + 1e-16f);
    float v = fmaxf(accv * (1.0f / 7.0f) + cbias[lane], 0.f);
    if (!FINAL) {
      hout[(size_t)n * 64 + lane] = f2bf(v);
    } else {
      // ---- output MLP, all within this wave (in-order DS, no barriers) ----
      int t = lane;
      hb[nw][t] = v;
      if (t < 32) {
        float a = c1[t];
        #pragma unroll
        for (int k = 0; k < 64; ++k) a += hb[nw][k] * V1[k * 32 + t];
        r1[nw][t] = fmaxf(a, 0.f);
      }
      if (t < 16) {
        float a = c2[t];
        #pragma unroll
        for (int k = 0; k < 32; ++k) a += r1[nw][k] * V2[k * 16 + t];
        r2[nw][t] = fmaxf(a, 0.f);
      }
      if (t < 9) {
        float a = c3[t];
        #pragma unroll
        for (int k = 0; k < 16; ++k) a += r2[nw][k] * V3[k * 9 + t];
        z3[nw][t] = a;
      }
      if (t < 9) {
        float mx = z3[nw][0];
        #pragma unroll
        for (int k = 1; k < 9; ++k) mx = fmaxf(mx, z3[nw][k]);
        float s = 0.f;
        #pragma unroll
        for (int k = 0; k < 9; ++k) s += __expf(z3[nw][k] - mx);
        out[(size_t)n * 9 + t] = z3[nw][t] - mx - logf(s);
      }
    }
  }
}

// ---------------------------------------------------------------------------
extern "C" void kernel_launch(void* const* d_in, const int* in_sizes, int n_in,
                              void* d_out, int out_size, void* d_ws, size_t ws_size,
                              hipStream_t stream) {
  const float* x   = (const float*)d_in[0];
  const int*   ei  = (const int*)d_in[1];
  const float* W1  = (const float*)d_in[2];
  const float* b1  = (const float*)d_in[3];
  const float* W2  = (const float*)d_in[4];
  const float* b2  = (const float*)d_in[5];
  const float* W3  = (const float*)d_in[6];
  const float* b3  = (const float*)d_in[7];
  const float* Wl  = (const float*)d_in[8];
  const float* bl  = (const float*)d_in[9];
  const float* Wr  = (const float*)d_in[10];
  const float* att = (const float*)d_in[11];
  const float* cb  = (const float*)d_in[12];
  const float* V1  = (const float*)d_in[13];
  const float* c1  = (const float*)d_in[14];
  const float* V2  = (const float*)d_in[15];
  const float* c2  = (const float*)d_in[16];
  const float* V3  = (const float*)d_in[17];
  const float* c3  = (const float*)d_in[18];
  float* out = (float*)d_out;

  char* ws = (char*)d_ws;
  size_t off = 0;
  auto alloc = [&](size_t bytes) {
    void* p = ws + off;
    off = (off + bytes + 255) & ~(size_t)255;
    return p;
  };
  // region0 (reused): xb (20.5MB) -> h2 -> xlt [N][1024] shorts
  char* region0 = (char*)alloc((size_t)NNODES * 1024 * 2 + 1024);
  short* xb  = (short*)region0;
  short* h2  = (short*)region0;
  short* xlt = (short*)region0;
  // region1 (reused): h1 (10.2MB) -> hA/hB
  char* region1 = (char*)alloc((size_t)NNODES * 512 * 2 + 1024);
  short* h1 = (short*)region1;
  short* hA = (short*)region1;
  short* hB = hA + (size_t)NNODES * 64;
  // persistent
  short* W1t = (short*)alloc((size_t)512 * 1024 * 2);
  short* W2t = (short*)alloc((size_t)256 * 512 * 2);
  short* W3t = (short*)alloc((size_t)64 * 256 * 2);
  short* Wgt = (short*)alloc((size_t)5 * HCP * 64 * 2);
  float* bg  = (float*)alloc((size_t)5 * HCP * 4);
  int* cnt       = (int*)alloc((size_t)NNODES * 4);
  int* row_start = (int*)alloc((size_t)(NNODES + 1) * 4);
  int* cursor    = (int*)alloc((size_t)NNODES * 4);
  int* csr_src   = (int*)alloc((size_t)ETOT * 4);
  int* csr_dst   = (int*)alloc((size_t)ETOT * 4);
  float* wbuf    = (float*)alloc((size_t)ETOT * 8 * 4);

  // ---- fused prep (convert + transposes + pack + cnt init)
  prep_kernel<<<(PTOT + 255) / 256, 256, 0, stream>>>(
      x, xb, W1, W1t, W2, W2t, W3, W3t, Wl, Wr, bl, Wgt, bg, cnt);

  // ---- CSR build (self-loops included)
  hist_kernel<<<(NEDGES + 255) / 256, 256, 0, stream>>>(ei, cnt);
  scan_kernel<<<1, 1024, 0, stream>>>(cnt, row_start, cursor);
  scatter_kernel<<<(ETOT + 255) / 256, 256, 0, stream>>>(ei, cursor, csr_src, csr_dst);

  // ---- input MLP (bf16 MFMA)
  mfma_gemm<64, 128, 1><<<dim3(157, 4), 256, 0, stream>>>(
      xb, W1t, b1, h1, NNODES, 1024, 512);
  mfma_gemm<64, 128, 1><<<dim3(157, 2), 256, 0, stream>>>(
      h1, W2t, b2, h2, NNODES, 512, 256);
  mfma_gemm<64, 64, 1><<<dim3(157, 1), 256, 0, stream>>>(
      h2, W3t, b3, hA, NNODES, 256, 64);

  // ---- 5 GATv2 layers
  short* hcur = hA;
  short* hnext = hB;
  for (int layer = 0; layer < 5; ++layer) {
    mfma_gemm<128, 128, 0><<<dim3(79, 8), 256, 0, stream>>>(
        hcur, Wgt + (size_t)layer * HCP * 64, bg + (size_t)layer * HCP, xlt,
        NNODES, 64, HCP);
    edge_logits_kernel<<<(ETOT + 31) / 32, 256, 0, stream>>>(
        xlt, att + (size_t)layer * HC, csr_src, csr_dst, wbuf);
    if (layer < 4) {
      gat_agg2_kernel<0><<<5000, 256, 0, stream>>>(
          xlt, wbuf, cb + (size_t)layer * 64, row_start, csr_src, hnext,
          V1, c1, V2, c2, V3, c3, out);
    } else {
      gat_agg2_kernel<1><<<5000, 256, 0, stream>>>(
          xlt, wbuf, cb + (size_t)layer * 64, row_start, csr_src, hnext,
          V1, c1, V2, c2, V3, c3, out);
    }
    short* tmp = hcur; hcur = hnext; hnext = tmp;
  }
}